// Round 1
// baseline (553.201 us; speedup 1.0000x reference)
//
#include <hip/hip_runtime.h>
#include <hip/hip_fp16.h>
#include <cstdint>
#include <cmath>

// ============================================================================
// Conv2dLayer (StyleGAN conv2d_resample up=2 k=3 + FIR [1,3,3,1] + bias_act)
// Decomposition: transposed-conv(stride2) ∘ depthwise-FIR == per-output-phase
// stride-1 3x3 conv over the 64x64 input with transformed weights:
//   W_eff[py,px][o][c][dy][dx] = sum_{by,bx} w[o][c][by][bx]*G[py][dy][by]*G[px][dx][bx]
// with G from f = [0.25,0.75,0.75,0.25] (FIR normalized * up-gain 2 per dim):
//   G[even] = {{0,f0,f1},{f1,f2,f3},{f3,0,0}}
//   G[odd ] = {{0,0,f0},{f0,f1,f2},{f2,f3,0}}
// Input tap for output (2i+py, 2j+px), shift (dy,dx) is x[i-1+dy, j-1+dx].
// => implicit GEMM  M=8*64*64=32768, N=1024 (o*4+p), K=9*512.
// fp16 MFMA (16x16x32), fp32 accumulate. W_eff scaled by 64 (epilogue /64).
// ============================================================================

typedef _Float16 f16;
typedef _Float16 f16x8 __attribute__((ext_vector_type(8)));
typedef _Float16 f16x4 __attribute__((ext_vector_type(4)));
typedef float f32x4 __attribute__((ext_vector_type(4)));

#define GLD16(g, l)                                                            \
  __builtin_amdgcn_global_load_lds(                                            \
      (const __attribute__((address_space(1))) void*)(g),                      \
      (__attribute__((address_space(3))) void*)(l), 16, 0, 0)

static const size_t XP_ELEMS  = (size_t)8 * 66 * 66 * 512;   // padded NHWC fp16
static const size_t XP_BYTES  = XP_ELEMS * 2;                // 35,684,352
static const size_t WEFF_ELEMS = (size_t)9 * 1024 * 512;
static const size_t WEFF_BYTES = WEFF_ELEMS * 2;             // 9,437,184

// ---------------------------------------------------------------------------
// Pre-pass 1: NCHW fp32 -> padded NHWC fp16 (pad=1 each side). One block per
// (n, h) image row; LDS transpose so both global read and write are coalesced.
// Pad ring is zeroed by a hipMemsetAsync on the whole XP region beforehand.
// ---------------------------------------------------------------------------
__global__ __launch_bounds__(256) void pad_transpose(const float* __restrict__ x,
                                                     f16* __restrict__ xp) {
  __shared__ f16 tile[64][68];  // [w][c_local], pad 68 to tame bank conflicts
  const int b = blockIdx.x;
  const int n = b >> 6, h = b & 63, y = h + 1;
  const int t = threadIdx.x;
  for (int c0 = 0; c0 < 512; c0 += 64) {
    if (c0) __syncthreads();
#pragma unroll
    for (int r = 0; r < 16; ++r) {
      int idx = r * 256 + t;
      int cl = idx >> 6, wpos = idx & 63;          // coalesced along wpos
      float v = x[(((size_t)(n * 512 + c0 + cl) * 64 + h) << 6) + wpos];
      tile[wpos][cl] = (f16)v;
    }
    __syncthreads();
#pragma unroll
    for (int q = 0; q < 4; ++q) {
      int st = q * 256 + t;
      int xw = st >> 4, c = (st & 15) << 2;        // 4 fp16 per store, 8B
      f16x4 v = *(const f16x4*)&tile[xw][c];
      *(f16x4*)&xp[((size_t)((n * 66 + y) * 66 + xw + 1) << 9) + c0 + c] = v;
    }
  }
}

// ---------------------------------------------------------------------------
// Pre-pass 2: weight transform -> W_eff[shift s=dy*3+dx][col=o*4+py*2+px][c]
// fp16, includes weight_gain 1/sqrt(512*9) and a *64 range scale.
// ---------------------------------------------------------------------------
__global__ __launch_bounds__(256) void weff_kernel(const float* __restrict__ w,
                                                   f16* __restrict__ weff) {
  const int g = blockIdx.x * 256 + threadIdx.x;   // 131072 = 256 o * 512 c
  const int o = g >> 9, c = g & 511;
  const float* wp = w + (size_t)(o * 512 + c) * 9;
  float w9[9];
#pragma unroll
  for (int k = 0; k < 9; ++k) w9[k] = wp[k];
  const float f0 = 0.25f, f1 = 0.75f, f2 = 0.75f, f3 = 0.25f;
  const float G[2][3][3] = {
      {{0.f, f0, f1}, {f1, f2, f3}, {f3, 0.f, 0.f}},
      {{0.f, 0.f, f0}, {f0, f1, f2}, {f2, f3, 0.f}}};
  const float scale = 64.f / sqrtf(512.f * 9.f);
#pragma unroll
  for (int py = 0; py < 2; ++py)
#pragma unroll
    for (int dy = 0; dy < 3; ++dy) {
      float ty[3];
#pragma unroll
      for (int bx = 0; bx < 3; ++bx)
        ty[bx] = w9[bx] * G[py][dy][0] + w9[3 + bx] * G[py][dy][1] +
                 w9[6 + bx] * G[py][dy][2];
#pragma unroll
      for (int px = 0; px < 2; ++px)
#pragma unroll
        for (int dx = 0; dx < 3; ++dx) {
          float v = ty[0] * G[px][dx][0] + ty[1] * G[px][dx][1] +
                    ty[2] * G[px][dx][2];
          int s = dy * 3 + dx;
          int col = (o << 2) | (py << 1) | px;
          weff[((size_t)(s * 1024 + col) << 9) + c] = (f16)(v * scale);
        }
    }
}

// ---------------------------------------------------------------------------
// Main: implicit-GEMM conv, m97 128x128 structure, 4 waves, BK=64.
// A tile: 128 pixels (2 image rows) x 64 ch from padded NHWC (shift = uniform
// address delta). B tile: 128 cols x 64 ch from W_eff. global_load_lds w=16,
// linear LDS dest + pre-swizzled global source (chunk ^= row&7) so the
// ds_read_b128 fragment reads are bank-conflict-free.
// ---------------------------------------------------------------------------
__global__ __launch_bounds__(256) void conv_main(const f16* __restrict__ xp,
                                                 const f16* __restrict__ weff,
                                                 const float* __restrict__ bias,
                                                 float* __restrict__ out) {
  __shared__ f16 ldsA[128 * 64];
  __shared__ f16 ldsB[128 * 64];
  const int t = threadIdx.x;
  const int lane = t & 63;
  const int wave = t >> 6;
  const int ntile = blockIdx.x;        // 0..7   (128 cols each)
  const int mtile = blockIdx.y;        // 0..255 (128 pixels each)
  const int n_img = mtile >> 5;
  const int i0 = (mtile & 31) << 1;    // first image row of the 2-row tile
  const int col0 = ntile << 7;

  // staging: chunk ch = t + 256q; pixel/col = ch/8; 8ch of channels = ch%8,
  // source channel chunk pre-swizzled by (row&7) to match read-side XOR.
  const int c_swz = ((t & 7) ^ ((t >> 3) & 7)) << 3;
  const f16* srcA[4];
  const f16* srcB[4];
#pragma unroll
  for (int q = 0; q < 4; ++q) {
    int pix = (t >> 3) + (q << 5);
    int il = pix >> 6, j = pix & 63;
    srcA[q] = xp + ((size_t)((n_img * 66 + i0 + il) * 66 + j) << 9) + c_swz;
    srcB[q] = weff + ((size_t)(col0 + (t >> 3) + (q << 5)) << 9) + c_swz;
  }
  f16* dstA = ldsA + t * 8;
  f16* dstB = ldsB + t * 8;

  f32x4 acc[4][4];
#pragma unroll
  for (int m = 0; m < 4; ++m)
#pragma unroll
    for (int n = 0; n < 4; ++n) {
      f32x4 z = {0.f, 0.f, 0.f, 0.f};
      acc[m][n] = z;
    }

  const int lrow = lane & 15;
  const int kgrp = lane >> 4;
  const int rA = (wave >> 1) << 6;   // wave's row base (0/64)
  const int cB = (wave & 1) << 6;    // wave's col base (0/64)

  for (int s = 0; s < 9; ++s) {
    const int offA_s = ((s / 3) * 66 + (s % 3)) << 9;  // (dy*66+dx)*512
    const int offB_s = s << 19;                        // s*1024*512
    for (int kc = 0; kc < 8; ++kc) {
      const int offA = offA_s + (kc << 6);
      const int offB = offB_s + (kc << 6);
      __syncthreads();
#pragma unroll
      for (int q = 0; q < 4; ++q) GLD16(srcA[q] + offA, dstA + q * 2048);
#pragma unroll
      for (int q = 0; q < 4; ++q) GLD16(srcB[q] + offB, dstB + q * 2048);
      __syncthreads();
#pragma unroll
      for (int kk = 0; kk < 2; ++kk) {
        const int cs = (((kk << 2) | kgrp) ^ (lrow & 7)) << 3;
        f16x8 a[4], b[4];
#pragma unroll
        for (int m = 0; m < 4; ++m)
          a[m] = *(const f16x8*)&ldsA[((rA + (m << 4) + lrow) << 6) + cs];
#pragma unroll
        for (int n = 0; n < 4; ++n)
          b[n] = *(const f16x8*)&ldsB[((cB + (n << 4) + lrow) << 6) + cs];
#pragma unroll
        for (int m = 0; m < 4; ++m)
#pragma unroll
          for (int n = 0; n < 4; ++n)
            acc[m][n] =
                __builtin_amdgcn_mfma_f32_16x16x32_f16(a[m], b[n], acc[m][n], 0, 0, 0);
      }
    }
  }

  // epilogue: /64 (W_eff scale), +bias, lrelu*sqrt(2), clamp, pixel-shuffle
  const float inv = 1.0f / 64.0f;
#pragma unroll
  for (int nf = 0; nf < 4; ++nf) {
    const int colL = cB + (nf << 4) + lrow;
    const int oG = (col0 + colL) >> 2;
    const int py = (colL >> 1) & 1, px = colL & 1;
    const float bz = bias[oG];
#pragma unroll
    for (int m = 0; m < 4; ++m) {
#pragma unroll
      for (int r = 0; r < 4; ++r) {
        const int rowL = rA + (m << 4) + (kgrp << 2) + r;
        const int ii = i0 + (rowL >> 6), jj = rowL & 63;
        float v = acc[m][nf][r] * inv + bz;
        v = (v < 0.f ? 0.2f * v : v) * 1.41421356237f;
        v = fminf(fmaxf(v, -256.f), 256.f);
        out[((size_t)((n_img * 256 + oG) * 128 + (ii << 1) + py) << 7) +
            (jj << 1) + px] = v;
      }
    }
  }
}

// ---------------------------------------------------------------------------
// Fallback (only if ws_size is too small): direct fp32, one thread per output.
// ---------------------------------------------------------------------------
__global__ void naive_conv(const float* __restrict__ x, const float* __restrict__ w,
                           const float* __restrict__ bias, float* __restrict__ out) {
  size_t g = (size_t)blockIdx.x * 256 + threadIdx.x;
  const int xo = g & 127, yo = (int)((g >> 7) & 127);
  const int o = (int)((g >> 14) & 255), n = (int)(g >> 22);
  const int px = xo & 1, py = yo & 1, j = xo >> 1, i = yo >> 1;
  const float f0 = 0.25f, f1 = 0.75f, f2 = 0.75f, f3 = 0.25f;
  const float G0[3][3] = {{0.f, f0, f1}, {f1, f2, f3}, {f3, 0.f, 0.f}};
  const float G1[3][3] = {{0.f, 0.f, f0}, {f0, f1, f2}, {f2, f3, 0.f}};
  const float(*Gy)[3] = py ? G1 : G0;
  const float(*Gx)[3] = px ? G1 : G0;
  float acc = 0.f;
  for (int c = 0; c < 512; ++c) {
    const float* wp = w + ((size_t)o * 512 + c) * 9;
    float w9[9];
#pragma unroll
    for (int k = 0; k < 9; ++k) w9[k] = wp[k];
    float ty[3][3];
#pragma unroll
    for (int dy = 0; dy < 3; ++dy)
#pragma unroll
      for (int bx = 0; bx < 3; ++bx)
        ty[dy][bx] = w9[bx] * Gy[dy][0] + w9[3 + bx] * Gy[dy][1] + w9[6 + bx] * Gy[dy][2];
#pragma unroll
    for (int dy = 0; dy < 3; ++dy) {
      int yy = i + dy - 1;
      if (yy < 0 || yy > 63) continue;
#pragma unroll
      for (int dx = 0; dx < 3; ++dx) {
        int xx = j + dx - 1;
        if (xx < 0 || xx > 63) continue;
        float eff = ty[dy][0] * Gx[dx][0] + ty[dy][1] * Gx[dx][1] + ty[dy][2] * Gx[dx][2];
        acc += x[(((size_t)(n * 512 + c) * 64 + yy) << 6) + xx] * eff;
      }
    }
  }
  float v = acc * (1.f / sqrtf(512.f * 9.f)) + bias[o];
  v = (v < 0.f ? 0.2f * v : v) * 1.41421356237f;
  v = fminf(fmaxf(v, -256.f), 256.f);
  out[g] = v;
}

extern "C" void kernel_launch(void* const* d_in, const int* in_sizes, int n_in,
                              void* d_out, int out_size, void* d_ws, size_t ws_size,
                              hipStream_t stream) {
  const float* x = (const float*)d_in[0];
  const float* w = (const float*)d_in[1];
  const float* bias = (const float*)d_in[2];
  float* out = (float*)d_out;

  const size_t NEED = XP_BYTES + WEFF_BYTES;
  if (ws_size < NEED) {
    naive_conv<<<131072, 256, 0, stream>>>(x, w, bias, out);
    return;
  }
  f16* xp = (f16*)d_ws;
  f16* weff = (f16*)((char*)d_ws + XP_BYTES);

  hipMemsetAsync(d_ws, 0, XP_BYTES, stream);           // zero pad ring
  pad_transpose<<<512, 256, 0, stream>>>(x, xp);       // NCHW f32 -> NHWC f16 padded
  weff_kernel<<<512, 256, 0, stream>>>(w, weff);       // weight transform
  conv_main<<<dim3(8, 256), 256, 0, stream>>>(xp, weff, bias, out);
}

// Round 4
// 477.704 us; speedup vs baseline: 1.1580x; 1.1580x over previous
//
#include <hip/hip_runtime.h>
#include <hip/hip_fp16.h>
#include <cstdint>
#include <cmath>

// ============================================================================
// Conv2dLayer (StyleGAN conv2d_resample up=2 k=3 + FIR [1,3,3,1] + bias_act)
// = per-output-phase stride-1 3x3 conv over 64x64 input (FIR folded into W):
//   implicit GEMM  M=8*64*64=32768, N=1024 (o*4+py*2+px), K=9*512.
// Round 4 == round 2/3 resubmit (both were infra failures; OOB/hang audit
// clean): 256x256 8-phase schedule (T2 swizzle + T3/T4 counted vmcnt + T5
// setprio), raw s_barrier (no vmcnt(0) drain), double-buffered 128 KiB LDS.
// ============================================================================

typedef _Float16 f16;
typedef _Float16 f16x8 __attribute__((ext_vector_type(8)));
typedef float f32x4 __attribute__((ext_vector_type(4)));

#define GLD16(g, l)                                                            \
  __builtin_amdgcn_global_load_lds(                                            \
      (const __attribute__((address_space(1))) void*)(g),                      \
      (__attribute__((address_space(3))) void*)(l), 16, 0, 0)

#define BAR()                                                                  \
  {                                                                            \
    __asm__ volatile("" ::: "memory");                                         \
    __builtin_amdgcn_s_barrier();                                              \
    __asm__ volatile("" ::: "memory");                                         \
  }
#define VMCNT(n) __asm__ volatile("s_waitcnt vmcnt(" #n ")" ::: "memory")

static const size_t XP_ELEMS = (size_t)8 * 66 * 66 * 512;  // padded NHWC fp16
static const size_t XP_BYTES = XP_ELEMS * 2;               // 35,684,352
static const size_t WEFF_ELEMS = (size_t)9 * 1024 * 512;
static const size_t WEFF_BYTES = WEFF_ELEMS * 2;           // 9,437,184

// ---------------------------------------------------------------------------
// Pre-pass 0: zero only the pad ring (2.1 MB), not the whole buffer.
// 520 blocks x 256 thr x one f16x8 chunk = exactly 8*260*64 chunks.
// ---------------------------------------------------------------------------
__global__ __launch_bounds__(256) void ring_zero(f16* __restrict__ xp) {
  int g = blockIdx.x * 256 + threadIdx.x;  // 133120
  int n = g / 16640, r = g % 16640;
  int seg = r >> 6, c8 = r & 63;
  int y, xc;
  if (seg < 66) {
    y = 0; xc = seg;
  } else if (seg < 132) {
    y = 65; xc = seg - 66;
  } else {
    int rem = seg - 132;
    y = 1 + (rem >> 1);
    xc = (rem & 1) * 65;
  }
  f16x8 z = {0, 0, 0, 0, 0, 0, 0, 0};
  *(f16x8*)&xp[((size_t)((n * 66 + y) * 66 + xc) << 9) + (c8 << 3)] = z;
}

// ---------------------------------------------------------------------------
// Pre-pass 1: NCHW fp32 -> padded NHWC fp16 interior. 2048 blocks, each one
// (n, h, 128-ch quarter); LDS transpose, coalesced both sides.
// ---------------------------------------------------------------------------
__global__ __launch_bounds__(256) void pad_transpose(const float* __restrict__ x,
                                                     f16* __restrict__ xp) {
  __shared__ f16 tile[64][132];  // [w][c_local], pad to 132
  const int b = blockIdx.x;      // n(8) * h(64) * cq(4)
  const int cq = b & 3, h = (b >> 2) & 63, n = b >> 8;
  const int t = threadIdx.x;
  const int c0 = cq << 7;
#pragma unroll
  for (int r = 0; r < 32; ++r) {
    int idx = r * 256 + t;
    int cl = idx >> 6, w = idx & 63;  // coalesced along w
    float v = x[(((size_t)(n * 512 + c0 + cl) * 64 + h) << 6) + w];
    tile[w][cl] = (f16)v;
  }
  __syncthreads();
#pragma unroll
  for (int q = 0; q < 4; ++q) {
    int ch = q * 256 + t;
    int w = ch >> 4, cc = ch & 15;
    f16x8 v = *(const f16x8*)&tile[w][cc << 3];
    *(f16x8*)&xp[((size_t)((n * 66 + h + 1) * 66 + w + 1) << 9) + c0 + (cc << 3)] = v;
  }
}

// ---------------------------------------------------------------------------
// Pre-pass 2: weight transform -> W_eff[s][col=o*4+py*2+px][c] fp16,
// includes weight_gain 1/sqrt(512*9) and *64 range scale (epilogue /64).
// ---------------------------------------------------------------------------
__global__ __launch_bounds__(256) void weff_kernel(const float* __restrict__ w,
                                                   f16* __restrict__ weff) {
  const int g = blockIdx.x * 256 + threadIdx.x;  // 131072 = 256 o * 512 c
  const int o = g >> 9, c = g & 511;
  const float* wp = w + (size_t)(o * 512 + c) * 9;
  float w9[9];
#pragma unroll
  for (int k = 0; k < 9; ++k) w9[k] = wp[k];
  const float f0 = 0.25f, f1 = 0.75f, f2 = 0.75f, f3 = 0.25f;
  const float G[2][3][3] = {
      {{0.f, f0, f1}, {f1, f2, f3}, {f3, 0.f, 0.f}},
      {{0.f, 0.f, f0}, {f0, f1, f2}, {f2, f3, 0.f}}};
  const float scale = 64.f / sqrtf(512.f * 9.f);
#pragma unroll
  for (int py = 0; py < 2; ++py)
#pragma unroll
    for (int dy = 0; dy < 3; ++dy) {
      float ty[3];
#pragma unroll
      for (int bx = 0; bx < 3; ++bx)
        ty[bx] = w9[bx] * G[py][dy][0] + w9[3 + bx] * G[py][dy][1] +
                 w9[6 + bx] * G[py][dy][2];
#pragma unroll
      for (int px = 0; px < 2; ++px)
#pragma unroll
        for (int dx = 0; dx < 3; ++dx) {
          float v = ty[0] * G[px][dx][0] + ty[1] * G[px][dx][1] +
                    ty[2] * G[px][dx][2];
          int s = dy * 3 + dx;
          int col = (o << 2) | (py << 1) | px;
          weff[((size_t)(s * 1024 + col) << 9) + c] = (f16)(v * scale);
        }
    }
}

// ---------------------------------------------------------------------------
// Main: 256x256 tile, BK=64, 8 waves (2M x 4N), 8-phase double-buffered
// schedule. LDS 128 KiB: A0|A1|B0|B1, each 256x64 f16 (16384), halves of
// 128 rows. Stage = 2x global_load_lds(16B) per half-tile per thread, linear
// LDS dest + pre-swizzled global source; frag ds_read_b128 with XOR swizzle.
// ---------------------------------------------------------------------------
__global__ __launch_bounds__(512, 2) void conv_main(const f16* __restrict__ xp,
                                                    const f16* __restrict__ weff,
                                                    const float* __restrict__ bias,
                                                    float* __restrict__ out) {
  __shared__ f16 lds[65536];
  f16* A0 = lds;
  f16* A1 = lds + 16384;
  f16* B0 = lds + 32768;
  f16* B1 = lds + 49152;

  const int t = threadIdx.x;
  const int lane = t & 63, wave = t >> 6;
  const int wm = wave >> 2, wn = wave & 3;  // 2M x 4N
  const int lrow = lane & 15, kgrp = lane >> 4;

  // XCD mapping: 512 wgs, 8 XCDs; XCD pair {2x,2x+1} owns ntile x
  // (B-panel 2.36 MB fits one XCD L2).
  const int d = blockIdx.x;
  const int xcd = d & 7, idx = d >> 3;       // idx 0..63
  const int ntile = xcd >> 1;                // 0..3
  const int mtile = ((xcd & 1) << 6) + idx;  // 0..127
  const int n_img = mtile >> 4;
  const int i0 = (mtile & 15) << 2;  // 4 image rows per tile
  const int col0 = ntile << 8;

  // --- staging addresses: chunk = q*512 + t -> (p_local = q*64 + t>>3, c8 = t&7)
  // pixel p = h*128 + p_local -> ii = h*2 + q, jj = t>>3. Source channel
  // chunk pre-swizzled: c8 ^ (p&7), p&7 == (t>>3)&7 for all q,h.
  const int c_swz = ((t & 7) ^ ((t >> 3) & 7)) << 3;
  const int jj = t >> 3;  // 0..63
  const f16* sA[2][2];
  const f16* sB[2][2];
#pragma unroll
  for (int q = 0; q < 2; ++q)
#pragma unroll
    for (int h = 0; h < 2; ++h) {
      sA[q][h] = xp + ((size_t)((n_img * 66 + i0 + h * 2 + q) * 66 + jj) << 9) + c_swz;
      sB[q][h] = weff + ((size_t)(col0 + h * 128 + q * 64 + jj) << 9) + c_swz;
    }

#define ST_A(buf, h, off)                                     \
  {                                                           \
    GLD16(sA[0][h] + (off), (buf) + (h)*8192 + t * 8);        \
    GLD16(sA[1][h] + (off), (buf) + (h)*8192 + 4096 + t * 8); \
  }
#define ST_B(buf, h, off)                                     \
  {                                                           \
    GLD16(sB[0][h] + (off), (buf) + (h)*8192 + t * 8);        \
    GLD16(sB[1][h] + (off), (buf) + (h)*8192 + 4096 + t * 8); \
  }

  // K-tile t -> shift s = t>>3 (dy=s/3, dx=s%3), channel chunk kc = t&7.
#define OFFS(tt, oa, ob)                                   \
  {                                                        \
    int s_ = (tt) >> 3, kc_ = (tt)&7;                      \
    int dy_ = s_ / 3, dx_ = s_ - 3 * dy_;                  \
    oa = ((dy_ * 66 + dx_) << 9) + (kc_ << 6);             \
    ob = (s_ << 19) + (kc_ << 6);                          \
  }

  f16x8 af[4][2];        // current mh-half A frags
  f16x8 bf[2][2][2];     // [nh][n][kk]
  f32x4 acc[8][4];
#pragma unroll
  for (int m = 0; m < 8; ++m)
#pragma unroll
    for (int n = 0; n < 4; ++n) {
      f32x4 z = {0.f, 0.f, 0.f, 0.f};
      acc[m][n] = z;
    }

#define LDA(bufp, mh)                                                          \
  _Pragma("unroll") for (int m = 0; m < 4; ++m) _Pragma("unroll") for (int kk = 0; kk < 2; ++kk) \
      af[m][kk] = *(const f16x8*)&(                                            \
          bufp)[((wm * 128 + (mh)*64 + m * 16 + lrow) << 6) +                  \
                ((((kk << 2) | kgrp) ^ (lrow & 7)) << 3)];

#define LDB(bufp, nh)                                                          \
  _Pragma("unroll") for (int n = 0; n < 2; ++n) _Pragma("unroll") for (int kk = 0; kk < 2; ++kk) \
      bf[nh][n][kk] = *(const f16x8*)&(                                        \
          bufp)[((wn * 64 + (nh)*32 + n * 16 + lrow) << 6) +                   \
                ((((kk << 2) | kgrp) ^ (lrow & 7)) << 3)];

#define MM(mh, nh)                                                             \
  __builtin_amdgcn_s_setprio(1);                                               \
  _Pragma("unroll") for (int kk = 0; kk < 2; ++kk)                             \
  _Pragma("unroll") for (int m = 0; m < 4; ++m)                                \
  _Pragma("unroll") for (int n = 0; n < 2; ++n)                                \
      acc[(mh)*4 + m][(nh)*2 + n] = __builtin_amdgcn_mfma_f32_16x16x32_f16(    \
          af[m][kk], bf[nh][n][kk], acc[(mh)*4 + m][(nh)*2 + n], 0, 0, 0);     \
  __builtin_amdgcn_s_setprio(0);

  // ---- prologue: stage tile0 -> buf0 (4 halves), A-half0 of tile1 -> buf1.
  {
    int oa0, ob0, oa1, ob1;
    OFFS(0, oa0, ob0);
    OFFS(1, oa1, ob1);
    ST_A(A0, 0, oa0);
    ST_A(A0, 1, oa0);
    ST_B(B0, 0, ob0);
    ST_B(B0, 1, ob0);
    ST_A(A1, 0, oa1);
    (void)ob1;
  }
  VMCNT(2);
  BAR();

  // ---- main loop: 36 iterations x 2 K-tiles (72 = 9 shifts x 8 ch-chunks)
  for (int j = 0; j < 36; ++j) {
    const int t1 = 2 * j + 1;
    int tn0 = t1 + 1;
    if (tn0 > 71) tn0 = 71;
    int tn1 = t1 + 2;
    if (tn1 > 71) tn1 = 71;
    int oa1, ob1, oan0, obn0, oan1, obn1;
    OFFS(t1, oa1, ob1);
    OFFS(tn0, oan0, obn0);
    OFFS(tn1, oan1, obn1);
    (void)obn1;

    // P1: frags A0[mh0], B0[nh0]; stage A1h1 (tile t1)
    LDA(A0, 0);
    LDB(B0, 0);
    ST_A(A1, 1, oa1);
    BAR();
    MM(0, 0);
    BAR();
    // P2: frags B0[nh1]; stage B1h0 (t1)
    LDB(B0, 1);
    ST_B(B1, 0, ob1);
    BAR();
    MM(0, 1);
    BAR();
    // P3: frags A0[mh1]; stage B1h1 (t1)
    LDA(A0, 1);
    ST_B(B1, 1, ob1);
    BAR();
    MM(1, 1);
    BAR();
    // P4: stage A0h0 (tile tn0); gate tile-t1 stages (8 drained, 2 in flight)
    ST_A(A0, 0, oan0);
    VMCNT(2);
    BAR();
    MM(1, 0);
    BAR();
    // P5: frags A1[mh0], B1[nh0]; stage A0h1 (tn0)
    LDA(A1, 0);
    LDB(B1, 0);
    ST_A(A0, 1, oan0);
    BAR();
    MM(0, 0);
    BAR();
    // P6: frags B1[nh1]; stage B0h0 (tn0)
    LDB(B1, 1);
    ST_B(B0, 0, obn0);
    BAR();
    MM(0, 1);
    BAR();
    // P7: frags A1[mh1]; stage B0h1 (tn0)
    LDA(A1, 1);
    ST_B(B0, 1, obn0);
    BAR();
    MM(1, 1);
    BAR();
    // P8: stage A1h0 (tile tn1); gate tile-tn0 stages
    ST_A(A1, 0, oan1);
    VMCNT(2);
    BAR();
    MM(1, 0);
    BAR();
  }
  VMCNT(0);

  // ---- epilogue: /64, +bias, lrelu*sqrt(2), clamp, pixel-shuffle store
  const float inv = 1.0f / 64.0f;
#pragma unroll
  for (int na = 0; na < 4; ++na) {
    const int colL = wn * 64 + na * 16 + lrow;
    const int col = col0 + colL;
    const int oG = col >> 2;
    const int py = (col >> 1) & 1, px = col & 1;
    const float bz = bias[oG];
#pragma unroll
    for (int ma = 0; ma < 8; ++ma) {
#pragma unroll
      for (int r = 0; r < 4; ++r) {
        const int rowL = wm * 128 + ma * 16 + (kgrp << 2) + r;
        const int ii = i0 + (rowL >> 6), j2 = rowL & 63;
        float v = acc[ma][na][r] * inv + bz;
        v = (v < 0.f ? 0.2f * v : v) * 1.41421356237f;
        v = fminf(fmaxf(v, -256.f), 256.f);
        out[((size_t)((n_img * 256 + oG) * 128 + (ii << 1) + py) << 7) +
            (j2 << 1) + px] = v;
      }
    }
  }
#undef ST_A
#undef ST_B
#undef OFFS
#undef LDA
#undef LDB
#undef MM
}

// ---------------------------------------------------------------------------
// Fallback (only if ws_size too small): direct fp32, one thread per output.
// ---------------------------------------------------------------------------
__global__ void naive_conv(const float* __restrict__ x, const float* __restrict__ w,
                           const float* __restrict__ bias, float* __restrict__ out) {
  size_t g = (size_t)blockIdx.x * 256 + threadIdx.x;
  const int xo = g & 127, yo = (int)((g >> 7) & 127);
  const int o = (int)((g >> 14) & 255), n = (int)(g >> 22);
  const int px = xo & 1, py = yo & 1, j = xo >> 1, i = yo >> 1;
  const float f0 = 0.25f, f1 = 0.75f, f2 = 0.75f, f3 = 0.25f;
  const float G0[3][3] = {{0.f, f0, f1}, {f1, f2, f3}, {f3, 0.f, 0.f}};
  const float G1[3][3] = {{0.f, 0.f, f0}, {f0, f1, f2}, {f2, f3, 0.f}};
  const float(*Gy)[3] = py ? G1 : G0;
  const float(*Gx)[3] = px ? G1 : G0;
  float acc = 0.f;
  for (int c = 0; c < 512; ++c) {
    const float* wp = w + ((size_t)o * 512 + c) * 9;
    float w9[9];
#pragma unroll
    for (int k = 0; k < 9; ++k) w9[k] = wp[k];
    float ty[3][3];
#pragma unroll
    for (int dy = 0; dy < 3; ++dy)
#pragma unroll
      for (int bx = 0; bx < 3; ++bx)
        ty[dy][bx] =
            w9[bx] * Gy[dy][0] + w9[3 + bx] * Gy[dy][1] + w9[6 + bx] * Gy[dy][2];
#pragma unroll
    for (int dy = 0; dy < 3; ++dy) {
      int yy = i + dy - 1;
      if (yy < 0 || yy > 63) continue;
#pragma unroll
      for (int dx = 0; dx < 3; ++dx) {
        int xx = j + dx - 1;
        if (xx < 0 || xx > 63) continue;
        float eff =
            ty[dy][0] * Gx[dx][0] + ty[dy][1] * Gx[dx][1] + ty[dy][2] * Gx[dx][2];
        acc += x[(((size_t)(n * 512 + c) * 64 + yy) << 6) + xx] * eff;
      }
    }
  }
  float v = acc * (1.f / sqrtf(512.f * 9.f)) + bias[o];
  v = (v < 0.f ? 0.2f * v : v) * 1.41421356237f;
  v = fminf(fmaxf(v, -256.f), 256.f);
  out[g] = v;
}

extern "C" void kernel_launch(void* const* d_in, const int* in_sizes, int n_in,
                              void* d_out, int out_size, void* d_ws, size_t ws_size,
                              hipStream_t stream) {
  const float* x = (const float*)d_in[0];
  const float* w = (const float*)d_in[1];
  const float* bias = (const float*)d_in[2];
  float* out = (float*)d_out;

  const size_t NEED = XP_BYTES + WEFF_BYTES;
  if (ws_size < NEED) {
    naive_conv<<<131072, 256, 0, stream>>>(x, w, bias, out);
    return;
  }
  f16* xp = (f16*)d_ws;
  f16* weff = (f16*)((char*)d_ws + XP_BYTES);

  ring_zero<<<520, 256, 0, stream>>>(xp);
  pad_transpose<<<2048, 256, 0, stream>>>(x, xp);
  weff_kernel<<<512, 256, 0, stream>>>(w, weff);
  conv_main<<<512, 512, 0, stream>>>(xp, weff, bias, out);
}